// Round 1
// 417.493 us; speedup vs baseline: 1.0837x; 1.0837x over previous
//
#include <hip/hip_runtime.h>
#include <hip/hip_fp16.h>
#include <math.h>

#define NB 16
#define NA 720
#define ND 1024
#define NH 512
#define NW 512

#define TW 64      // tile width  (x)
#define TH 8       // tile height (y)
#define PXT 2      // y-pixels per thread
#define NBT 8      // batches per block
#define WINN 68    // window entries (span <= sqrt(63^2+7^2)+3 ~ 66.4)
#define GROUP 16   // angles per fp16-accumulate group (720 = 45*16)

typedef __fp16 h2vec __attribute__((ext_vector_type(2)));

__device__ __forceinline__ uint32_t pkrtz_u32(float a, float b) {
    union { h2vec h; uint32_t u; } v;
    v.h = __builtin_amdgcn_cvt_pkrtz(a, b);   // one v_cvt_pkrtz_f16_f32
    return v.u;
}
__device__ __forceinline__ __half2 u32_to_h2(uint32_t u) {
    union { uint32_t u; __half2 h; } v; v.u = u; return v.h;
}
__device__ __forceinline__ uint32_t h2_to_u32(__half2 h) {
    union { __half2 h; uint32_t u; } v; v.h = h; return v.u;
}

// ---------------------------------------------------------------------------
// Kernel 0: per-(tile-position, angle) parameter table. 512 positions x 720
// angles x 16B. Entry: (c, s, 511.5-base, bits(a*ND+base)). Computed once so
// the backproj kernel reads params via uniform s_load (SMEM pipe) instead of
// re-deriving them in VALU every angle (no scalar FP unit on CDNA).
// ---------------------------------------------------------------------------
__global__ __launch_bounds__(768) void prep_kernel(float4* __restrict__ ptable) {
    const int a = threadIdx.x;
    const int pos = blockIdx.x;
    if (a >= NA) return;
    const float step = (float)(M_PI / (double)NA);
    float s, c;
    sincosf((float)a * step, &s, &c);
    const int bx = pos & 7, by = pos >> 3;
    const float x0 = (float)(bx * TW) - 255.5f;
    const float x1 = x0 + (float)(TW - 1);
    const float y0 = (float)(by * TH) - 255.5f;
    // s >= 0 for angles in [0, pi): min over y at y0.
    const float tmin = 511.5f + fminf(x0 * c, x1 * c) + y0 * s;
    const int base = (int)floorf(tmin) - 1;
    ptable[pos * NA + a] = make_float4(c, s, 511.5f - (float)base,
                                       __int_as_float(a * ND + base));
}

// ---------------------------------------------------------------------------
// Kernel 1: ramp filter via in-LDS Stockham radix-2 FFT (fp32). Pairs the two
// rows of a BATCH-PAIR at the SAME angle: z = x_{2p} + i*x_{2p+1}; filter is
// real & even-symmetric so Y = filt*Z; IFFT -> Re = batch 2p, Im = batch 2p+1.
// Output is fp16-PACKED u32 (h(f_2p[i]), h(f_2p+1[i])) written into the row
// slot of batch 2p, angle a -- block-local in-place safe for the d_in[0]
// fallback (reads complete into LDS before stores). 1/ND norm folded in.
// ---------------------------------------------------------------------------
__global__ __launch_bounds__(256) void filter_kernel(const float* __restrict__ sino,
                                                     const float* __restrict__ filt,
                                                     uint32_t* __restrict__ packed) {
    __shared__ float2 bufA[ND];
    __shared__ float2 bufB[ND];
    __shared__ float2 tw[ND / 2];   // tw[m] = exp(-2*pi*i*m/ND)

    const int tid = threadIdx.x;
    const int a = blockIdx.x;       // angle
    const int p = blockIdx.y;       // batch pair
    const float* __restrict__ xa = sino + ((size_t)(2 * p) * NA + a) * ND;
    const float* __restrict__ xb = xa + (size_t)NA * ND;
    uint32_t* __restrict__ yo = packed + ((size_t)(2 * p) * NA + a) * ND;

    #pragma unroll
    for (int i = 0; i < ND; i += 256)
        bufA[i + tid] = make_float2(xa[i + tid], xb[i + tid]);
    #pragma unroll
    for (int i = 0; i < ND / 2; i += 256) {
        int m = i + tid;
        float ang = (float)(-2.0 * M_PI / (double)ND) * (float)m;
        float s, c;
        sincosf(ang, &s, &c);
        tw[m] = make_float2(c, s);
    }
    __syncthreads();

    float2* src = bufA;
    float2* dst = bufB;

    // forward FFT: Stockham, Ns = 1..512
    for (int Ns = 1; Ns < ND; Ns <<= 1) {
        #pragma unroll
        for (int q = 0; q < ND / 2; q += 256) {
            int j = q + tid;
            int m = j & (Ns - 1);
            float2 v0 = src[j];
            float2 v1 = src[j + ND / 2];
            float2 w = tw[m * (ND / 2 / Ns)];
            float tr = w.x * v1.x - w.y * v1.y;
            float ti = w.x * v1.y + w.y * v1.x;
            int d = ((j & ~(Ns - 1)) << 1) + m;
            dst[d]      = make_float2(v0.x + tr, v0.y + ti);
            dst[d + Ns] = make_float2(v0.x - tr, v0.y - ti);
        }
        __syncthreads();
        float2* tmp = src; src = dst; dst = tmp;
    }

    // multiply by real filter, with 1/ND folded in
    const float SCALE = 1.0f / (float)ND;
    #pragma unroll
    for (int i = 0; i < ND; i += 256) {
        float f = filt[i + tid] * SCALE;
        src[i + tid].x *= f;
        src[i + tid].y *= f;
    }
    __syncthreads();

    // inverse FFT: same flow with conjugated twiddles
    for (int Ns = 1; Ns < ND; Ns <<= 1) {
        #pragma unroll
        for (int q = 0; q < ND / 2; q += 256) {
            int j = q + tid;
            int m = j & (Ns - 1);
            float2 v0 = src[j];
            float2 v1 = src[j + ND / 2];
            float2 w = tw[m * (ND / 2 / Ns)];
            float tr = w.x * v1.x + w.y * v1.y;   // conj(w)*v1
            float ti = w.x * v1.y - w.y * v1.x;
            int d = ((j & ~(Ns - 1)) << 1) + m;
            dst[d]      = make_float2(v0.x + tr, v0.y + ti);
            dst[d + Ns] = make_float2(v0.x - tr, v0.y - ti);
        }
        __syncthreads();
        float2* tmp = src; src = dst; dst = tmp;
    }

    #pragma unroll
    for (int i = 0; i < ND; i += 256)
        yo[i + tid] = pkrtz_u32(src[i + tid].x, src[i + tid].y);
}

// ---------------------------------------------------------------------------
// Kernel 2: backprojection. 64x8 tile x 8 batches per 256-thread block
// (grid unchanged at 1024 blocks -> 4 blocks/CU). Params via uniform s_load
// from ptable (0 VALU). LDS window entry is a fused uint4
// (f01|f23 with precomputed deltas): ONE ds_read_b128 serves FOUR batches'
// lerps, so the per-k inner loop is 2x b128 + 8 pk-fp16 ops for 8 batches
// (was 2x b64 + 4 pk ops for 4). This halves LDS wave-instructions per
// batch-pixel -- the measured bottleneck (LDS per-instr overhead ~4cyc:
// 140 b64/CU/angle * ~8cyc = 336us model vs 362us measured).
// FOUR phases, TWO angles per barrier (360 barriers): sub-round A computes
// phases 0,1, writes held angles into 2,3, issues loads; sub-round B mirrors.
// Phases are compile-time; the it-loop is NOT unrolled (R8: deep unroll
// spills). fp16 acc flushed to fp32 every GROUP=16 angles. Bounds check
// eliminated: |px*c+py*s| <= 361.3 < 511.5; local index in [1,65] < WINN=68.
// ---------------------------------------------------------------------------
__global__ __launch_bounds__(256, 4) void backproj_kernel(const uint32_t* __restrict__ packed,
                                                          const float4* __restrict__ ptable,
                                                          float* __restrict__ img) {
    // win[sg][ph][i]: sg=0 -> batches 0..3 (pairs 4bz+0,4bz+1),
    //                 sg=1 -> batches 4..7 (pairs 4bz+2,4bz+3)
    // entry = (fA, dfA, fB, dfB) fp16-packed; 2*4*68*16B = 8704 B
    __shared__ __align__(16) uint4 win[2][4][WINN];

    const int tid = threadIdx.x;
    const int bx = blockIdx.x, by = blockIdx.y, bz = blockIdx.z;

    const float4* __restrict__ pt = ptable + (size_t)((by << 3) + bx) * NA;

    // staging: threads 0..135; sg selects batch quad (0: b0..3 / 1: b4..7)
    const bool stg = tid < 2 * WINN;
    const int sg   = (tid >= WINN) ? 1 : 0;
    const int si   = tid - sg * WINN;
    // packed row slot of pair p (batch 2p), angle a, detector i:
    //   packed[((2p)*NA + a)*ND + i];  this thread's pairs: 4bz+2sg, 4bz+2sg+1
    const uint32_t* __restrict__ sbA =
        packed + (size_t)(2 * (4 * bz + 2 * sg)) * NA * ND + si;
    const uint32_t* __restrict__ sbB = sbA + (size_t)2 * NA * ND;
    uint4* const wptr = &win[sg][0][si];

    const int tx  = tid & (TW - 1);
    const int ty0 = (tid >> 6) * PXT;
    const float px  = (float)(bx * TW + tx)  - 255.5f;
    const float pyf = (float)(by * TH + ty0) - 255.5f;

    float accf[8][PXT];
    __half2 hacc01[PXT], hacc23[PXT], hacc45[PXT], hacc67[PXT];
    #pragma unroll
    for (int k = 0; k < PXT; k++) {
        #pragma unroll
        for (int b = 0; b < 8; b++) accf[b][k] = 0.0f;
        hacc01[k] = u32_to_h2(0u); hacc23[k] = u32_to_h2(0u);
        hacc45[k] = u32_to_h2(0u); hacc67[k] = u32_to_h2(0u);
    }

    auto stage_load = [&](float4 P, uint2& wA, uint2& wB) {
        const int off = __float_as_int(P.w);
        const uint32_t* pa = sbA + off;
        const uint32_t* pb = sbB + off;
        wA = make_uint2(pa[0], pa[1]);
        wB = make_uint2(pb[0], pb[1]);
    };
    auto stage_write = [&](int ph, uint2 wA, uint2 wB) {
        wptr[ph * WINN] = make_uint4(
            wA.x, h2_to_u32(__hsub2(u32_to_h2(wA.y), u32_to_h2(wA.x))),
            wB.x, h2_to_u32(__hsub2(u32_to_h2(wB.y), u32_to_h2(wB.x))));
    };
    auto compute = [&](float4 P, int ph) {
        const float sy = P.y;
        const float tb = fmaf(px, P.x, fmaf(pyf, sy, P.z));
        #pragma unroll
        for (int k = 0; k < PXT; k++) {
            float t  = fmaf((float)k, sy, tb);
            int   i0 = (int)t;                    // t > 0 -> trunc == floor
#if __has_builtin(__builtin_amdgcn_fractf)
            float w  = __builtin_amdgcn_fractf(t);
#else
            float w  = t - (float)i0;
#endif
            __half2 wh2 = u32_to_h2(pkrtz_u32(w, w));   // one pkrtz
            const uint4 qA = win[0][ph][i0];            // ds_read_b128
            const uint4 qB = win[1][ph][i0];            // ds_read_b128 (+imm)
            hacc01[k] = __hfma2(wh2, u32_to_h2(qA.y), __hadd2(hacc01[k], u32_to_h2(qA.x)));
            hacc23[k] = __hfma2(wh2, u32_to_h2(qA.w), __hadd2(hacc23[k], u32_to_h2(qA.z)));
            hacc45[k] = __hfma2(wh2, u32_to_h2(qB.y), __hadd2(hacc45[k], u32_to_h2(qB.x)));
            hacc67[k] = __hfma2(wh2, u32_to_h2(qB.w), __hadd2(hacc67[k], u32_to_h2(qB.z)));
        }
    };

    // prologue: stage angles 0,1 into phases 0,1; hold raw loads of 2,3
    uint2 h2A = make_uint2(0, 0), h2B = make_uint2(0, 0);
    uint2 h3A = make_uint2(0, 0), h3B = make_uint2(0, 0);
    if (stg) {
        uint2 wA, wB;
        stage_load(pt[0], wA, wB);  stage_write(0, wA, wB);
        stage_load(pt[1], wA, wB);  stage_write(1, wA, wB);
        stage_load(pt[2], h2A, h2B);
        stage_load(pt[3], h3A, h3B);
    }
    __syncthreads();

    for (int g = 0; g < NA; g += GROUP) {
        #pragma unroll 1
        for (int it = 0; it < GROUP / 4; it++) {
            const int a = g + it * 4;
            // params a..a+7 via uniform s_load (a+4.. clamped; only .w used
            // for staging addresses of angles that are never computed OOB)
            const float4 P0 = pt[a],     P1 = pt[a + 1];
            const float4 P2 = pt[a + 2], P3 = pt[a + 3];
            const float4 P4 = pt[min(a + 4, NA - 1)], P5 = pt[min(a + 5, NA - 1)];
            const float4 P6 = pt[min(a + 6, NA - 1)], P7 = pt[min(a + 7, NA - 1)];

            // ---- sub-round A: compute a, a+1 (ph 0,1) ----
            uint2 l4A = make_uint2(0, 0), l4B = make_uint2(0, 0);
            uint2 l5A = make_uint2(0, 0), l5B = make_uint2(0, 0);
            if (stg) {
                stage_load(P4, l4A, l4B);        // angle a+4 (consumed in B)
                stage_load(P5, l5A, l5B);        // angle a+5
                stage_write(2, h2A, h2B);        // angle a+2 -> ph2
                stage_write(3, h3A, h3B);        // angle a+3 -> ph3
            }
            compute(P0, 0);
            compute(P1, 1);
            __syncthreads();

            // ---- sub-round B: compute a+2, a+3 (ph 2,3) ----
            uint2 l6A = make_uint2(0, 0), l6B = make_uint2(0, 0);
            uint2 l7A = make_uint2(0, 0), l7B = make_uint2(0, 0);
            if (stg) {
                stage_load(P6, l6A, l6B);        // angle a+6 (held to next it)
                stage_load(P7, l7A, l7B);        // angle a+7
                stage_write(0, l4A, l4B);        // angle a+4 -> ph0
                stage_write(1, l5A, l5B);        // angle a+5 -> ph1
            }
            compute(P2, 2);
            compute(P3, 3);
            h2A = l6A; h2B = l6B; h3A = l7A; h3B = l7B;
            __syncthreads();
        }
        // flush fp16 group accumulators into fp32
        #pragma unroll
        for (int k = 0; k < PXT; k++) {
            float2 v01 = __half22float2(hacc01[k]);
            float2 v23 = __half22float2(hacc23[k]);
            float2 v45 = __half22float2(hacc45[k]);
            float2 v67 = __half22float2(hacc67[k]);
            accf[0][k] += v01.x; accf[1][k] += v01.y;
            accf[2][k] += v23.x; accf[3][k] += v23.y;
            accf[4][k] += v45.x; accf[5][k] += v45.y;
            accf[6][k] += v67.x; accf[7][k] += v67.y;
            hacc01[k] = u32_to_h2(0u); hacc23[k] = u32_to_h2(0u);
            hacc45[k] = u32_to_h2(0u); hacc67[k] = u32_to_h2(0u);
        }
    }

    const float SCALE = (float)(M_PI / (double)NA);
    const size_t bstride = (size_t)NH * NW;
    size_t o0 = (((size_t)(bz * NBT) * NH) + (by * TH + ty0)) * NW + (bx * TW + tx);
    #pragma unroll
    for (int k = 0; k < PXT; k++) {
        #pragma unroll
        for (int b = 0; b < 8; b++)
            img[o0 + (size_t)k * NW + (size_t)b * bstride] = accf[b][k] * SCALE;
    }
}

// ---------------------------------------------------------------------------
extern "C" void kernel_launch(void* const* d_in, const int* in_sizes, int n_in,
                              void* d_out, int out_size, void* d_ws, size_t ws_size,
                              hipStream_t stream) {
    const float* sino = (const float*)d_in[0];
    const float* filt = (const float*)d_in[1];
    float* out = (float*)d_out;

    // packed buffer occupies the even-batch row slots of a full-size
    // (NB*NA*ND u32) region — same footprint as the old fp32 filtered buffer.
    const size_t pack_bytes = (size_t)NB * NA * ND * sizeof(uint32_t);
    const size_t ptab_bytes = (size_t)512 * NA * sizeof(float4);
    uint32_t* packed;
    float4* ptable;
    if (ws_size >= pack_bytes + ptab_bytes) {
        packed = (uint32_t*)d_ws;
        ptable = (float4*)((char*)d_ws + pack_bytes);
    } else {
        // fallback: pack in-place into the input (filter writes are
        // block-local: each block overwrites only the row it read) and put
        // the params table in d_ws.
        packed = (uint32_t*)d_in[0];
        ptable = (float4*)d_ws;
    }

    prep_kernel<<<dim3(512), dim3(768), 0, stream>>>(ptable);
    filter_kernel<<<dim3(NA, NB / 2), dim3(256), 0, stream>>>(sino, filt, packed);
    backproj_kernel<<<dim3(NW / TW, NH / TH, NB / NBT), dim3(256), 0, stream>>>(packed, ptable, out);
}

// Round 2
// 409.324 us; speedup vs baseline: 1.1053x; 1.0200x over previous
//
#include <hip/hip_runtime.h>
#include <hip/hip_fp16.h>
#include <math.h>

#define NB 16
#define NA 720
#define ND 1024
#define NH 512
#define NW 512

#define TW 64      // tile width  (x)
#define TH 8       // tile height (y)
#define PXT 2      // y-pixels per thread
#define NBT 8      // batches per block
#define WINN 68    // window entries (span <= sqrt(63^2+7^2)+3 ~ 66.4)
#define GROUP 16   // angles per fp16-accumulate group (720 = 45*16)

typedef __fp16 h2vec __attribute__((ext_vector_type(2)));

__device__ __forceinline__ uint32_t pkrtz_u32(float a, float b) {
    union { h2vec h; uint32_t u; } v;
    v.h = __builtin_amdgcn_cvt_pkrtz(a, b);   // one v_cvt_pkrtz_f16_f32
    return v.u;
}
__device__ __forceinline__ __half2 u32_to_h2(uint32_t u) {
    union { uint32_t u; __half2 h; } v; v.u = u; return v.h;
}
__device__ __forceinline__ uint32_t h2_to_u32(__half2 h) {
    union { __half2 h; uint32_t u; } v; v.h = h; return v.u;
}

// ---------------------------------------------------------------------------
// Kernel 0: per-(tile-position, angle) parameter table. 512 positions x 720
// angles x 16B. Entry: (c, s, 511.5-base, bits(a*ND+base)). Computed once so
// the backproj kernel reads params via uniform s_load (SMEM pipe) instead of
// re-deriving them in VALU every angle (no scalar FP unit on CDNA).
// ---------------------------------------------------------------------------
__global__ __launch_bounds__(768) void prep_kernel(float4* __restrict__ ptable) {
    const int a = threadIdx.x;
    const int pos = blockIdx.x;
    if (a >= NA) return;
    const float step = (float)(M_PI / (double)NA);
    float s, c;
    sincosf((float)a * step, &s, &c);
    const int bx = pos & 7, by = pos >> 3;
    const float x0 = (float)(bx * TW) - 255.5f;
    const float x1 = x0 + (float)(TW - 1);
    const float y0 = (float)(by * TH) - 255.5f;
    // s >= 0 for angles in [0, pi): min over y at y0.
    const float tmin = 511.5f + fminf(x0 * c, x1 * c) + y0 * s;
    const int base = (int)floorf(tmin) - 1;
    ptable[pos * NA + a] = make_float4(c, s, 511.5f - (float)base,
                                       __int_as_float(a * ND + base));
}

// ---------------------------------------------------------------------------
// Kernel 1: ramp filter via in-LDS Stockham radix-2 FFT (fp32). Pairs the two
// rows of a BATCH-PAIR at the SAME angle: z = x_{2p} + i*x_{2p+1}; filter is
// real & even-symmetric so Y = filt*Z; IFFT -> Re = batch 2p, Im = batch 2p+1.
// Output is fp16-PACKED u32 (h(f_2p[i]), h(f_2p+1[i])) written into the row
// slot of batch 2p, angle a -- block-local in-place safe for the d_in[0]
// fallback (reads complete into LDS before stores). 1/ND norm folded in.
// ---------------------------------------------------------------------------
__global__ __launch_bounds__(256) void filter_kernel(const float* __restrict__ sino,
                                                     const float* __restrict__ filt,
                                                     uint32_t* __restrict__ packed) {
    __shared__ float2 bufA[ND];
    __shared__ float2 bufB[ND];
    __shared__ float2 tw[ND / 2];   // tw[m] = exp(-2*pi*i*m/ND)

    const int tid = threadIdx.x;
    const int a = blockIdx.x;       // angle
    const int p = blockIdx.y;       // batch pair
    const float* __restrict__ xa = sino + ((size_t)(2 * p) * NA + a) * ND;
    const float* __restrict__ xb = xa + (size_t)NA * ND;
    uint32_t* __restrict__ yo = packed + ((size_t)(2 * p) * NA + a) * ND;

    #pragma unroll
    for (int i = 0; i < ND; i += 256)
        bufA[i + tid] = make_float2(xa[i + tid], xb[i + tid]);
    #pragma unroll
    for (int i = 0; i < ND / 2; i += 256) {
        int m = i + tid;
        float ang = (float)(-2.0 * M_PI / (double)ND) * (float)m;
        float s, c;
        sincosf(ang, &s, &c);
        tw[m] = make_float2(c, s);
    }
    __syncthreads();

    float2* src = bufA;
    float2* dst = bufB;

    // forward FFT: Stockham, Ns = 1..512
    for (int Ns = 1; Ns < ND; Ns <<= 1) {
        #pragma unroll
        for (int q = 0; q < ND / 2; q += 256) {
            int j = q + tid;
            int m = j & (Ns - 1);
            float2 v0 = src[j];
            float2 v1 = src[j + ND / 2];
            float2 w = tw[m * (ND / 2 / Ns)];
            float tr = w.x * v1.x - w.y * v1.y;
            float ti = w.x * v1.y + w.y * v1.x;
            int d = ((j & ~(Ns - 1)) << 1) + m;
            dst[d]      = make_float2(v0.x + tr, v0.y + ti);
            dst[d + Ns] = make_float2(v0.x - tr, v0.y - ti);
        }
        __syncthreads();
        float2* tmp = src; src = dst; dst = tmp;
    }

    // multiply by real filter, with 1/ND folded in
    const float SCALE = 1.0f / (float)ND;
    #pragma unroll
    for (int i = 0; i < ND; i += 256) {
        float f = filt[i + tid] * SCALE;
        src[i + tid].x *= f;
        src[i + tid].y *= f;
    }
    __syncthreads();

    // inverse FFT: same flow with conjugated twiddles
    for (int Ns = 1; Ns < ND; Ns <<= 1) {
        #pragma unroll
        for (int q = 0; q < ND / 2; q += 256) {
            int j = q + tid;
            int m = j & (Ns - 1);
            float2 v0 = src[j];
            float2 v1 = src[j + ND / 2];
            float2 w = tw[m * (ND / 2 / Ns)];
            float tr = w.x * v1.x + w.y * v1.y;   // conj(w)*v1
            float ti = w.x * v1.y - w.y * v1.x;
            int d = ((j & ~(Ns - 1)) << 1) + m;
            dst[d]      = make_float2(v0.x + tr, v0.y + ti);
            dst[d + Ns] = make_float2(v0.x - tr, v0.y - ti);
        }
        __syncthreads();
        float2* tmp = src; src = dst; dst = tmp;
    }

    #pragma unroll
    for (int i = 0; i < ND; i += 256)
        yo[i + tid] = pkrtz_u32(src[i + tid].x, src[i + tid].y);
}

// ---------------------------------------------------------------------------
// Kernel 2: backprojection. 64x8 tile x 8 batches per 256-thread block
// (grid 1024 blocks -> 4 blocks/CU). Params via uniform s_load from ptable
// (0 VALU). LDS window entry is a fused uint4 (f01|f23 with precomputed
// deltas): ONE ds_read_b128 serves FOUR batches' lerps.
// LANE MAP (R2): wave = 16x x 4y pixel patch (lane = (x&15, y)), thread's 2
// k-pixels at y and y+4. The b128 gather address is 16*i0 with
// i0 ~ c*x + s*y: per wave-instruction the t-span is 16|c|+4|s| (max ~17,
// avg ~13) instead of the previous 64|c| (max 64) -> <=2.3 bank-rows per
// gather vs 8, heavy same-address broadcast. R1 measured 4.16e7 conflict
// cycles (~3.5 cyc/instr, ~68us) from the 64x1 map; this map removes them
// with zero change to per-pixel arithmetic (bit-identical output).
// FOUR phases, TWO angles per barrier (360 barriers): sub-round A computes
// phases 0,1, writes held angles into 2,3, issues loads; sub-round B mirrors.
// Phases are compile-time; the it-loop is NOT unrolled (R8: deep unroll
// spills). fp16 acc flushed to fp32 every GROUP=16 angles. Bounds check
// eliminated: |px*c+py*s| <= 361.3 < 511.5; local index in [1,65] < WINN=68.
// ---------------------------------------------------------------------------
__global__ __launch_bounds__(256, 4) void backproj_kernel(const uint32_t* __restrict__ packed,
                                                          const float4* __restrict__ ptable,
                                                          float* __restrict__ img) {
    // win[sg][ph][i]: sg=0 -> batches 0..3 (pairs 4bz+0,4bz+1),
    //                 sg=1 -> batches 4..7 (pairs 4bz+2,4bz+3)
    // entry = (fA, dfA, fB, dfB) fp16-packed; 2*4*68*16B = 8704 B
    __shared__ __align__(16) uint4 win[2][4][WINN];

    const int tid = threadIdx.x;
    const int bx = blockIdx.x, by = blockIdx.y, bz = blockIdx.z;

    const float4* __restrict__ pt = ptable + (size_t)((by << 3) + bx) * NA;

    // staging: threads 0..135; sg selects batch quad (0: b0..3 / 1: b4..7)
    const bool stg = tid < 2 * WINN;
    const int sg   = (tid >= WINN) ? 1 : 0;
    const int si   = tid - sg * WINN;
    // packed row slot of pair p (batch 2p), angle a, detector i:
    //   packed[((2p)*NA + a)*ND + i];  this thread's pairs: 4bz+2sg, 4bz+2sg+1
    const uint32_t* __restrict__ sbA =
        packed + (size_t)(2 * (4 * bz + 2 * sg)) * NA * ND + si;
    const uint32_t* __restrict__ sbB = sbA + (size_t)2 * NA * ND;
    uint4* const wptr = &win[sg][0][si];

    // lane map: wave = 16x x 4y; thread's k-pixels at y = ty0 + 4k
    const int lane = tid & 63;
    const int wid  = tid >> 6;
    const int tx   = (wid << 4) + (lane & 15);
    const int ty0  = lane >> 4;                       // 0..3
    const float px  = (float)(bx * TW + tx)  - 255.5f;
    const float pyf = (float)(by * TH + ty0) - 255.5f;

    float accf[8][PXT];
    __half2 hacc01[PXT], hacc23[PXT], hacc45[PXT], hacc67[PXT];
    #pragma unroll
    for (int k = 0; k < PXT; k++) {
        #pragma unroll
        for (int b = 0; b < 8; b++) accf[b][k] = 0.0f;
        hacc01[k] = u32_to_h2(0u); hacc23[k] = u32_to_h2(0u);
        hacc45[k] = u32_to_h2(0u); hacc67[k] = u32_to_h2(0u);
    }

    auto stage_load = [&](float4 P, uint2& wA, uint2& wB) {
        const int off = __float_as_int(P.w);
        const uint32_t* pa = sbA + off;
        const uint32_t* pb = sbB + off;
        wA = make_uint2(pa[0], pa[1]);
        wB = make_uint2(pb[0], pb[1]);
    };
    auto stage_write = [&](int ph, uint2 wA, uint2 wB) {
        wptr[ph * WINN] = make_uint4(
            wA.x, h2_to_u32(__hsub2(u32_to_h2(wA.y), u32_to_h2(wA.x))),
            wB.x, h2_to_u32(__hsub2(u32_to_h2(wB.y), u32_to_h2(wB.x))));
    };
    auto compute = [&](float4 P, int ph) {
        const float sy = P.y;
        const float tb = fmaf(px, P.x, fmaf(pyf, sy, P.z));
        #pragma unroll
        for (int k = 0; k < PXT; k++) {
            float t  = fmaf((float)(4 * k), sy, tb);   // y-step 4 per k
            int   i0 = (int)t;                    // t > 0 -> trunc == floor
#if __has_builtin(__builtin_amdgcn_fractf)
            float w  = __builtin_amdgcn_fractf(t);
#else
            float w  = t - (float)i0;
#endif
            __half2 wh2 = u32_to_h2(pkrtz_u32(w, w));   // one pkrtz
            const uint4 qA = win[0][ph][i0];            // ds_read_b128
            const uint4 qB = win[1][ph][i0];            // ds_read_b128 (+imm)
            hacc01[k] = __hfma2(wh2, u32_to_h2(qA.y), __hadd2(hacc01[k], u32_to_h2(qA.x)));
            hacc23[k] = __hfma2(wh2, u32_to_h2(qA.w), __hadd2(hacc23[k], u32_to_h2(qA.z)));
            hacc45[k] = __hfma2(wh2, u32_to_h2(qB.y), __hadd2(hacc45[k], u32_to_h2(qB.x)));
            hacc67[k] = __hfma2(wh2, u32_to_h2(qB.w), __hadd2(hacc67[k], u32_to_h2(qB.z)));
        }
    };

    // prologue: stage angles 0,1 into phases 0,1; hold raw loads of 2,3
    uint2 h2A = make_uint2(0, 0), h2B = make_uint2(0, 0);
    uint2 h3A = make_uint2(0, 0), h3B = make_uint2(0, 0);
    if (stg) {
        uint2 wA, wB;
        stage_load(pt[0], wA, wB);  stage_write(0, wA, wB);
        stage_load(pt[1], wA, wB);  stage_write(1, wA, wB);
        stage_load(pt[2], h2A, h2B);
        stage_load(pt[3], h3A, h3B);
    }
    __syncthreads();

    for (int g = 0; g < NA; g += GROUP) {
        #pragma unroll 1
        for (int it = 0; it < GROUP / 4; it++) {
            const int a = g + it * 4;
            // params a..a+7 via uniform s_load (a+4.. clamped; only .w used
            // for staging addresses of angles that are never computed OOB)
            const float4 P0 = pt[a],     P1 = pt[a + 1];
            const float4 P2 = pt[a + 2], P3 = pt[a + 3];
            const float4 P4 = pt[min(a + 4, NA - 1)], P5 = pt[min(a + 5, NA - 1)];
            const float4 P6 = pt[min(a + 6, NA - 1)], P7 = pt[min(a + 7, NA - 1)];

            // ---- sub-round A: compute a, a+1 (ph 0,1) ----
            uint2 l4A = make_uint2(0, 0), l4B = make_uint2(0, 0);
            uint2 l5A = make_uint2(0, 0), l5B = make_uint2(0, 0);
            if (stg) {
                stage_load(P4, l4A, l4B);        // angle a+4 (consumed in B)
                stage_load(P5, l5A, l5B);        // angle a+5
                stage_write(2, h2A, h2B);        // angle a+2 -> ph2
                stage_write(3, h3A, h3B);        // angle a+3 -> ph3
            }
            compute(P0, 0);
            compute(P1, 1);
            __syncthreads();

            // ---- sub-round B: compute a+2, a+3 (ph 2,3) ----
            uint2 l6A = make_uint2(0, 0), l6B = make_uint2(0, 0);
            uint2 l7A = make_uint2(0, 0), l7B = make_uint2(0, 0);
            if (stg) {
                stage_load(P6, l6A, l6B);        // angle a+6 (held to next it)
                stage_load(P7, l7A, l7B);        // angle a+7
                stage_write(0, l4A, l4B);        // angle a+4 -> ph0
                stage_write(1, l5A, l5B);        // angle a+5 -> ph1
            }
            compute(P2, 2);
            compute(P3, 3);
            h2A = l6A; h2B = l6B; h3A = l7A; h3B = l7B;
            __syncthreads();
        }
        // flush fp16 group accumulators into fp32
        #pragma unroll
        for (int k = 0; k < PXT; k++) {
            float2 v01 = __half22float2(hacc01[k]);
            float2 v23 = __half22float2(hacc23[k]);
            float2 v45 = __half22float2(hacc45[k]);
            float2 v67 = __half22float2(hacc67[k]);
            accf[0][k] += v01.x; accf[1][k] += v01.y;
            accf[2][k] += v23.x; accf[3][k] += v23.y;
            accf[4][k] += v45.x; accf[5][k] += v45.y;
            accf[6][k] += v67.x; accf[7][k] += v67.y;
            hacc01[k] = u32_to_h2(0u); hacc23[k] = u32_to_h2(0u);
            hacc45[k] = u32_to_h2(0u); hacc67[k] = u32_to_h2(0u);
        }
    }

    const float SCALE = (float)(M_PI / (double)NA);
    const size_t bstride = (size_t)NH * NW;
    // y-row of k-pixel: by*TH + ty0 + 4k
    size_t o0 = (((size_t)(bz * NBT) * NH) + (by * TH + ty0)) * NW + (bx * TW + tx);
    #pragma unroll
    for (int k = 0; k < PXT; k++) {
        #pragma unroll
        for (int b = 0; b < 8; b++)
            img[o0 + (size_t)(4 * k) * NW + (size_t)b * bstride] = accf[b][k] * SCALE;
    }
}

// ---------------------------------------------------------------------------
extern "C" void kernel_launch(void* const* d_in, const int* in_sizes, int n_in,
                              void* d_out, int out_size, void* d_ws, size_t ws_size,
                              hipStream_t stream) {
    const float* sino = (const float*)d_in[0];
    const float* filt = (const float*)d_in[1];
    float* out = (float*)d_out;

    // packed buffer occupies the even-batch row slots of a full-size
    // (NB*NA*ND u32) region — same footprint as the old fp32 filtered buffer.
    const size_t pack_bytes = (size_t)NB * NA * ND * sizeof(uint32_t);
    const size_t ptab_bytes = (size_t)512 * NA * sizeof(float4);
    uint32_t* packed;
    float4* ptable;
    if (ws_size >= pack_bytes + ptab_bytes) {
        packed = (uint32_t*)d_ws;
        ptable = (float4*)((char*)d_ws + pack_bytes);
    } else {
        // fallback: pack in-place into the input (filter writes are
        // block-local: each block overwrites only the row it read) and put
        // the params table in d_ws.
        packed = (uint32_t*)d_in[0];
        ptable = (float4*)d_ws;
    }

    prep_kernel<<<dim3(512), dim3(768), 0, stream>>>(ptable);
    filter_kernel<<<dim3(NA, NB / 2), dim3(256), 0, stream>>>(sino, filt, packed);
    backproj_kernel<<<dim3(NW / TW, NH / TH, NB / NBT), dim3(256), 0, stream>>>(packed, ptable, out);
}

// Round 3
// 377.065 us; speedup vs baseline: 1.1999x; 1.0856x over previous
//
#include <hip/hip_runtime.h>
#include <hip/hip_fp16.h>
#include <math.h>

#define NB 16
#define NA 720
#define ND 1024
#define NH 512
#define NW 512

#define TW 64      // tile width  (x)
#define TH 8       // tile height (y)
#define PXT 2      // x-subtiles per thread (8x8 lane map: k steps x by 8)
#define NBT 8      // batches per block
#define WINN 68    // window entries (span <= 63|c|+7|s| + 3 ~ 66.4)
#define GROUP 16   // angles per fp16-accumulate group (720 = 45*16)

typedef __fp16 h2vec __attribute__((ext_vector_type(2)));

__device__ __forceinline__ uint32_t pkrtz_u32(float a, float b) {
    union { h2vec h; uint32_t u; } v;
    v.h = __builtin_amdgcn_cvt_pkrtz(a, b);   // one v_cvt_pkrtz_f16_f32
    return v.u;
}
__device__ __forceinline__ __half2 u32_to_h2(uint32_t u) {
    union { uint32_t u; __half2 h; } v; v.u = u; return v.h;
}
__device__ __forceinline__ uint32_t h2_to_u32(__half2 h) {
    union { __half2 h; uint32_t u; } v; v.h = h; return v.u;
}

// ---------------------------------------------------------------------------
// Kernel 0: per-(tile-position, angle) parameter table. 512 positions x 720
// angles x 16B. Entry: (c, s, 511.5-base, bits(a*ND+base)). Computed once so
// the backproj kernel reads params via uniform s_load (SMEM pipe) instead of
// re-deriving them in VALU every angle (no scalar FP unit on CDNA).
// ---------------------------------------------------------------------------
__global__ __launch_bounds__(768) void prep_kernel(float4* __restrict__ ptable) {
    const int a = threadIdx.x;
    const int pos = blockIdx.x;
    if (a >= NA) return;
    const float step = (float)(M_PI / (double)NA);
    float s, c;
    sincosf((float)a * step, &s, &c);
    const int bx = pos & 7, by = pos >> 3;
    const float x0 = (float)(bx * TW) - 255.5f;
    const float x1 = x0 + (float)(TW - 1);
    const float y0 = (float)(by * TH) - 255.5f;
    // s >= 0 for angles in [0, pi): min over y at y0.
    const float tmin = 511.5f + fminf(x0 * c, x1 * c) + y0 * s;
    const int base = (int)floorf(tmin) - 1;
    ptable[pos * NA + a] = make_float4(c, s, 511.5f - (float)base,
                                       __int_as_float(a * ND + base));
}

// ---------------------------------------------------------------------------
// Kernel 1 (R3): ramp filter via in-LDS Stockham RADIX-4 FFT (fp32).
// 1024 = 4^5: 5 passes per direction instead of 10 (radix-2), ~45% fewer
// LDS instructions and half the barriers. All LDS buffer indices go through
// an XOR granule swizzle SZ(i) = i ^ ((i>>4)&15): the radix-2 version's
// early-stage writes (stride-2/4 float2) were 8-16-way bank conflicted;
// with SZ every stage's read AND write pattern lands on the 4-way floor
// (64 lanes x 8 B = 512 B = 4 cyc minimum per b64 wave-op).
// Pairs the two rows of a BATCH-PAIR at the SAME angle:
// z = x_{2p} + i*x_{2p+1}; filter is real & even-symmetric so Y = filt*Z;
// IFFT -> Re = batch 2p, Im = batch 2p+1. Output is fp16-PACKED u32
// (h(f_2p[i]), h(f_2p+1[i])) written into the row slot of batch 2p, angle a
// -- block-local in-place safe for the d_in[0] fallback. 1/ND norm folded in.
// Butterfly (verified on N=16 by hand): j = b*Ns + m, u_p = src[j + p*N/4]
// * tw[p*m*(N/(4Ns))]; outputs at d + r*Ns, d = ((j & ~(Ns-1))<<2) + m:
// y0 = A+C, y2 = A-C, y1/y3 = Bb -/+ i*D (forward; swapped for inverse),
// A = u0+u2, Bb = u0-u2, C = u1+u3, D = u1-u3.
// ---------------------------------------------------------------------------
#define SZ(i) ((i) ^ (((i) >> 4) & 15))

__device__ __forceinline__ float2 cmul(float2 w, float2 v) {
    return make_float2(w.x * v.x - w.y * v.y, w.x * v.y + w.y * v.x);
}
__device__ __forceinline__ float2 cmulc(float2 w, float2 v) {  // conj(w)*v
    return make_float2(w.x * v.x + w.y * v.y, w.x * v.y - w.y * v.x);
}

__global__ __launch_bounds__(256) void filter_kernel(const float* __restrict__ sino,
                                                     const float* __restrict__ filt,
                                                     uint32_t* __restrict__ packed) {
    __shared__ float2 bufA[ND];
    __shared__ float2 bufB[ND];
    __shared__ float2 tw4[768];   // tw4[t] = exp(-2*pi*i*t/ND), t < 3N/4

    const int tid = threadIdx.x;
    const int a = blockIdx.x;       // angle
    const int p = blockIdx.y;       // batch pair
    const float* __restrict__ xa = sino + ((size_t)(2 * p) * NA + a) * ND;
    const float* __restrict__ xb = xa + (size_t)NA * ND;
    uint32_t* __restrict__ yo = packed + ((size_t)(2 * p) * NA + a) * ND;

    #pragma unroll
    for (int i = 0; i < ND; i += 256)
        bufA[SZ(i + tid)] = make_float2(xa[i + tid], xb[i + tid]);
    #pragma unroll
    for (int i = 0; i < 768; i += 256) {
        int m = i + tid;
        float ang = (float)(-2.0 * M_PI / (double)ND) * (float)m;
        float s, c;
        sincosf(ang, &s, &c);
        tw4[SZ(m)] = make_float2(c, s);
    }
    __syncthreads();

    float2* src = bufA;
    float2* dst = bufB;

    // forward FFT: Stockham radix-4, Ns = 1,4,16,64,256 (j = tid: one
    // butterfly per thread per stage, 256 = ND/4)
    for (int Ns = 1; Ns < ND; Ns <<= 2) {
        const int j = tid;
        const int m = j & (Ns - 1);
        const int tstep = (ND / 4) / Ns;
        float2 u0 = src[SZ(j)];
        float2 x1 = src[SZ(j + 256)];
        float2 x2 = src[SZ(j + 512)];
        float2 x3 = src[SZ(j + 768)];
        float2 w1 = tw4[SZ(m * tstep)];
        float2 w2 = tw4[SZ(2 * m * tstep)];
        float2 w3 = tw4[SZ(3 * m * tstep)];
        float2 u1 = cmul(w1, x1), u2 = cmul(w2, x2), u3 = cmul(w3, x3);
        float2 A  = make_float2(u0.x + u2.x, u0.y + u2.y);
        float2 Bb = make_float2(u0.x - u2.x, u0.y - u2.y);
        float2 C  = make_float2(u1.x + u3.x, u1.y + u3.y);
        float2 D  = make_float2(u1.x - u3.x, u1.y - u3.y);
        const int d = ((j & ~(Ns - 1)) << 2) + m;
        dst[SZ(d)]          = make_float2(A.x + C.x, A.y + C.y);
        dst[SZ(d + Ns)]     = make_float2(Bb.x + D.y, Bb.y - D.x);   // -i*D
        dst[SZ(d + 2 * Ns)] = make_float2(A.x - C.x, A.y - C.y);
        dst[SZ(d + 3 * Ns)] = make_float2(Bb.x - D.y, Bb.y + D.x);   // +i*D
        __syncthreads();
        float2* tmp = src; src = dst; dst = tmp;
    }

    // multiply by real filter, with 1/ND folded in
    const float SCALE = 1.0f / (float)ND;
    #pragma unroll
    for (int i = 0; i < ND; i += 256) {
        float f = filt[i + tid] * SCALE;
        src[SZ(i + tid)].x *= f;
        src[SZ(i + tid)].y *= f;
    }
    __syncthreads();

    // inverse FFT: conjugated twiddles, y1/y3 swapped (+i/-i)
    for (int Ns = 1; Ns < ND; Ns <<= 2) {
        const int j = tid;
        const int m = j & (Ns - 1);
        const int tstep = (ND / 4) / Ns;
        float2 u0 = src[SZ(j)];
        float2 x1 = src[SZ(j + 256)];
        float2 x2 = src[SZ(j + 512)];
        float2 x3 = src[SZ(j + 768)];
        float2 w1 = tw4[SZ(m * tstep)];
        float2 w2 = tw4[SZ(2 * m * tstep)];
        float2 w3 = tw4[SZ(3 * m * tstep)];
        float2 u1 = cmulc(w1, x1), u2 = cmulc(w2, x2), u3 = cmulc(w3, x3);
        float2 A  = make_float2(u0.x + u2.x, u0.y + u2.y);
        float2 Bb = make_float2(u0.x - u2.x, u0.y - u2.y);
        float2 C  = make_float2(u1.x + u3.x, u1.y + u3.y);
        float2 D  = make_float2(u1.x - u3.x, u1.y - u3.y);
        const int d = ((j & ~(Ns - 1)) << 2) + m;
        dst[SZ(d)]          = make_float2(A.x + C.x, A.y + C.y);
        dst[SZ(d + Ns)]     = make_float2(Bb.x - D.y, Bb.y + D.x);   // +i*D
        dst[SZ(d + 2 * Ns)] = make_float2(A.x - C.x, A.y - C.y);
        dst[SZ(d + 3 * Ns)] = make_float2(Bb.x + D.y, Bb.y - D.x);   // -i*D
        __syncthreads();
        float2* tmp = src; src = dst; dst = tmp;
    }

    #pragma unroll
    for (int i = 0; i < ND; i += 256) {
        float2 v = src[SZ(i + tid)];
        yo[i + tid] = pkrtz_u32(v.x, v.y);
    }
}

// ---------------------------------------------------------------------------
// Kernel 2: backprojection. 64x8 tile x 8 batches per 256-thread block
// (grid 1024 blocks -> 4 blocks/CU). Params via uniform s_load from ptable
// (0 VALU). LDS window entry is a fused uint4 (f01|f23 with precomputed
// deltas): ONE ds_read_b128 serves FOUR batches' lerps.
// LANE MAP (R3): wave = 8x x 8y pixel patch (lane = (x&7, y)), thread's 2
// k-subtiles step x by 8 (x = 16*wid + 8*k + (lane&7)). Per-gather t-span is
// 8|c|+8|s| (avg 10.2, worst 11.3 entries) vs R2's 16|c|+4|s| (avg 12.7,
// worst 16.5): R1->R2 showed conflicts scale with span (4.16e7 -> 1.96e7);
// this map cuts the average span another ~20% with identical per-pixel
// arithmetic. FOUR phases, TWO angles per barrier (360 barriers): sub-round
// A computes phases 0,1, writes held angles into 2,3, issues loads; B
// mirrors. it-loop NOT unrolled (deep unroll spills). fp16 acc flushed to
// fp32 every GROUP=16 angles. Bounds check eliminated: |px*c+py*s| <= 361.3
// < 511.5; local index in [1,66] < WINN=68.
// ---------------------------------------------------------------------------
__global__ __launch_bounds__(256, 4) void backproj_kernel(const uint32_t* __restrict__ packed,
                                                          const float4* __restrict__ ptable,
                                                          float* __restrict__ img) {
    // win[sg][ph][i]: sg=0 -> batches 0..3 (pairs 4bz+0,4bz+1),
    //                 sg=1 -> batches 4..7 (pairs 4bz+2,4bz+3)
    // entry = (fA, dfA, fB, dfB) fp16-packed; 2*4*68*16B = 8704 B
    __shared__ __align__(16) uint4 win[2][4][WINN];

    const int tid = threadIdx.x;
    const int bx = blockIdx.x, by = blockIdx.y, bz = blockIdx.z;

    const float4* __restrict__ pt = ptable + (size_t)((by << 3) + bx) * NA;

    // staging: threads 0..135; sg selects batch quad (0: b0..3 / 1: b4..7)
    const bool stg = tid < 2 * WINN;
    const int sg   = (tid >= WINN) ? 1 : 0;
    const int si   = tid - sg * WINN;
    // packed row slot of pair p (batch 2p), angle a, detector i:
    //   packed[((2p)*NA + a)*ND + i];  this thread's pairs: 4bz+2sg, 4bz+2sg+1
    const uint32_t* __restrict__ sbA =
        packed + (size_t)(2 * (4 * bz + 2 * sg)) * NA * ND + si;
    const uint32_t* __restrict__ sbB = sbA + (size_t)2 * NA * ND;
    uint4* const wptr = &win[sg][0][si];

    // lane map: wave = 8x x 8y; thread's k-subtiles at x = 16*wid + 8k + x7
    const int lane = tid & 63;
    const int wid  = tid >> 6;
    const int tx0  = (wid << 4) + (lane & 7);         // k adds 8
    const int ty   = lane >> 3;                       // 0..7
    const float px  = (float)(bx * TW + tx0) - 255.5f;
    const float pyf = (float)(by * TH + ty)  - 255.5f;

    float accf[8][PXT];
    __half2 hacc01[PXT], hacc23[PXT], hacc45[PXT], hacc67[PXT];
    #pragma unroll
    for (int k = 0; k < PXT; k++) {
        #pragma unroll
        for (int b = 0; b < 8; b++) accf[b][k] = 0.0f;
        hacc01[k] = u32_to_h2(0u); hacc23[k] = u32_to_h2(0u);
        hacc45[k] = u32_to_h2(0u); hacc67[k] = u32_to_h2(0u);
    }

    auto stage_load = [&](float4 P, uint2& wA, uint2& wB) {
        const int off = __float_as_int(P.w);
        const uint32_t* pa = sbA + off;
        const uint32_t* pb = sbB + off;
        wA = make_uint2(pa[0], pa[1]);
        wB = make_uint2(pb[0], pb[1]);
    };
    auto stage_write = [&](int ph, uint2 wA, uint2 wB) {
        wptr[ph * WINN] = make_uint4(
            wA.x, h2_to_u32(__hsub2(u32_to_h2(wA.y), u32_to_h2(wA.x))),
            wB.x, h2_to_u32(__hsub2(u32_to_h2(wB.y), u32_to_h2(wB.x))));
    };
    auto compute = [&](float4 P, int ph) {
        const float tb = fmaf(px, P.x, fmaf(pyf, P.y, P.z));
        #pragma unroll
        for (int k = 0; k < PXT; k++) {
            float t  = fmaf((float)(8 * k), P.x, tb);  // x-step 8 per k
            int   i0 = (int)t;                    // t > 0 -> trunc == floor
#if __has_builtin(__builtin_amdgcn_fractf)
            float w  = __builtin_amdgcn_fractf(t);
#else
            float w  = t - (float)i0;
#endif
            __half2 wh2 = u32_to_h2(pkrtz_u32(w, w));   // one pkrtz
            const uint4 qA = win[0][ph][i0];            // ds_read_b128
            const uint4 qB = win[1][ph][i0];            // ds_read_b128 (+imm)
            hacc01[k] = __hfma2(wh2, u32_to_h2(qA.y), __hadd2(hacc01[k], u32_to_h2(qA.x)));
            hacc23[k] = __hfma2(wh2, u32_to_h2(qA.w), __hadd2(hacc23[k], u32_to_h2(qA.z)));
            hacc45[k] = __hfma2(wh2, u32_to_h2(qB.y), __hadd2(hacc45[k], u32_to_h2(qB.x)));
            hacc67[k] = __hfma2(wh2, u32_to_h2(qB.w), __hadd2(hacc67[k], u32_to_h2(qB.z)));
        }
    };

    // prologue: stage angles 0,1 into phases 0,1; hold raw loads of 2,3
    uint2 h2A = make_uint2(0, 0), h2B = make_uint2(0, 0);
    uint2 h3A = make_uint2(0, 0), h3B = make_uint2(0, 0);
    if (stg) {
        uint2 wA, wB;
        stage_load(pt[0], wA, wB);  stage_write(0, wA, wB);
        stage_load(pt[1], wA, wB);  stage_write(1, wA, wB);
        stage_load(pt[2], h2A, h2B);
        stage_load(pt[3], h3A, h3B);
    }
    __syncthreads();

    for (int g = 0; g < NA; g += GROUP) {
        #pragma unroll 1
        for (int it = 0; it < GROUP / 4; it++) {
            const int a = g + it * 4;
            // params a..a+7 via uniform s_load (a+4.. clamped; only .w used
            // for staging addresses of angles that are never computed OOB)
            const float4 P0 = pt[a],     P1 = pt[a + 1];
            const float4 P2 = pt[a + 2], P3 = pt[a + 3];
            const float4 P4 = pt[min(a + 4, NA - 1)], P5 = pt[min(a + 5, NA - 1)];
            const float4 P6 = pt[min(a + 6, NA - 1)], P7 = pt[min(a + 7, NA - 1)];

            // ---- sub-round A: compute a, a+1 (ph 0,1) ----
            uint2 l4A = make_uint2(0, 0), l4B = make_uint2(0, 0);
            uint2 l5A = make_uint2(0, 0), l5B = make_uint2(0, 0);
            if (stg) {
                stage_load(P4, l4A, l4B);        // angle a+4 (consumed in B)
                stage_load(P5, l5A, l5B);        // angle a+5
                stage_write(2, h2A, h2B);        // angle a+2 -> ph2
                stage_write(3, h3A, h3B);        // angle a+3 -> ph3
            }
            compute(P0, 0);
            compute(P1, 1);
            __syncthreads();

            // ---- sub-round B: compute a+2, a+3 (ph 2,3) ----
            uint2 l6A = make_uint2(0, 0), l6B = make_uint2(0, 0);
            uint2 l7A = make_uint2(0, 0), l7B = make_uint2(0, 0);
            if (stg) {
                stage_load(P6, l6A, l6B);        // angle a+6 (held to next it)
                stage_load(P7, l7A, l7B);        // angle a+7
                stage_write(0, l4A, l4B);        // angle a+4 -> ph0
                stage_write(1, l5A, l5B);        // angle a+5 -> ph1
            }
            compute(P2, 2);
            compute(P3, 3);
            h2A = l6A; h2B = l6B; h3A = l7A; h3B = l7B;
            __syncthreads();
        }
        // flush fp16 group accumulators into fp32
        #pragma unroll
        for (int k = 0; k < PXT; k++) {
            float2 v01 = __half22float2(hacc01[k]);
            float2 v23 = __half22float2(hacc23[k]);
            float2 v45 = __half22float2(hacc45[k]);
            float2 v67 = __half22float2(hacc67[k]);
            accf[0][k] += v01.x; accf[1][k] += v01.y;
            accf[2][k] += v23.x; accf[3][k] += v23.y;
            accf[4][k] += v45.x; accf[5][k] += v45.y;
            accf[6][k] += v67.x; accf[7][k] += v67.y;
            hacc01[k] = u32_to_h2(0u); hacc23[k] = u32_to_h2(0u);
            hacc45[k] = u32_to_h2(0u); hacc67[k] = u32_to_h2(0u);
        }
    }

    const float SCALE = (float)(M_PI / (double)NA);
    const size_t bstride = (size_t)NH * NW;
    // pixel of k-subtile: row by*TH + ty, col bx*TW + tx0 + 8k
    size_t o0 = (((size_t)(bz * NBT) * NH) + (by * TH + ty)) * NW + (bx * TW + tx0);
    #pragma unroll
    for (int k = 0; k < PXT; k++) {
        #pragma unroll
        for (int b = 0; b < 8; b++)
            img[o0 + (size_t)(8 * k) + (size_t)b * bstride] = accf[b][k] * SCALE;
    }
}

// ---------------------------------------------------------------------------
extern "C" void kernel_launch(void* const* d_in, const int* in_sizes, int n_in,
                              void* d_out, int out_size, void* d_ws, size_t ws_size,
                              hipStream_t stream) {
    const float* sino = (const float*)d_in[0];
    const float* filt = (const float*)d_in[1];
    float* out = (float*)d_out;

    // packed buffer occupies the even-batch row slots of a full-size
    // (NB*NA*ND u32) region — same footprint as the old fp32 filtered buffer.
    const size_t pack_bytes = (size_t)NB * NA * ND * sizeof(uint32_t);
    const size_t ptab_bytes = (size_t)512 * NA * sizeof(float4);
    uint32_t* packed;
    float4* ptable;
    if (ws_size >= pack_bytes + ptab_bytes) {
        packed = (uint32_t*)d_ws;
        ptable = (float4*)((char*)d_ws + pack_bytes);
    } else {
        // fallback: pack in-place into the input (filter writes are
        // block-local: each block overwrites only the row it read) and put
        // the params table in d_ws.
        packed = (uint32_t*)d_in[0];
        ptable = (float4*)d_ws;
    }

    prep_kernel<<<dim3(512), dim3(768), 0, stream>>>(ptable);
    filter_kernel<<<dim3(NA, NB / 2), dim3(256), 0, stream>>>(sino, filt, packed);
    backproj_kernel<<<dim3(NW / TW, NH / TH, NB / NBT), dim3(256), 0, stream>>>(packed, ptable, out);
}